// Round 1
// baseline (794.083 us; speedup 1.0000x reference)
//
#include <hip/hip_runtime.h>

// Problem constants (N=8192 tokens, D=256 model dim, dropout p=0.5 -> keep scale 2.0)
#define NT 8192
#define DM 256

typedef float f32x16 __attribute__((ext_vector_type(16)));
typedef __bf16 bf16x8 __attribute__((ext_vector_type(8)));

#define MFMA32(a, b, c) __builtin_amdgcn_mfma_f32_32x32x16_bf16((a), (b), (c), 0, 0, 0)
#define NEG_INF (-__builtin_inff())

static __device__ __forceinline__ unsigned short f2bf_bits(float f) {
  return __builtin_bit_cast(unsigned short, (__bf16)f);
}
static __device__ __forceinline__ float exp2_fast(float x) {
  return __builtin_amdgcn_exp2f(x);
}
// async global->LDS, 16B per lane. LDS dest is wave-uniform base + lane*16.
static __device__ __forceinline__ void gload_lds16(const void* g, void* l) {
  __builtin_amdgcn_global_load_lds(
      (const __attribute__((address_space(1))) unsigned int*)g,
      (__attribute__((address_space(3))) unsigned int*)l, 16, 0, 0);
}

// ---------------------------------------------------------------------------
// Kernel 0: classify drop_mask storage. 1 = int32 {0,1}, 2 = float32 {0,1.0f},
// 0 = uint8 bytes. Scans first 256 dwords.
// ---------------------------------------------------------------------------
__global__ void detect_kernel(const unsigned int* __restrict__ m, int* __restrict__ flag) {
  __shared__ int s01, sf;
  int t = threadIdx.x;
  if (t == 0) { s01 = 1; sf = 1; }
  __syncthreads();
  unsigned int v = m[t];
  if (v > 1u) atomicAnd(&s01, 0);
  if (v != 0u && v != 0x3F800000u) atomicAnd(&sf, 0);
  __syncthreads();
  if (t == 0) *flag = s01 ? 1 : (sf ? 2 : 0);
}

// ---------------------------------------------------------------------------
// Kernel 1: QKV projection. X[8192][256] f32, W[256][256] f32 (torch layout,
// out = X @ W^T). Outputs bf16: Qs (pre-scaled by log2(e)/16), K, and V stored
// transposed Vt[256][8192].
// grid (128 row-blocks, 3 mats), block 256.
// ---------------------------------------------------------------------------
__global__ __launch_bounds__(256) void proj_kernel(
    const float* __restrict__ X, const float* __restrict__ Wq,
    const float* __restrict__ Wk, const float* __restrict__ Wv,
    unsigned short* __restrict__ Qs, unsigned short* __restrict__ Kb,
    unsigned short* __restrict__ Vt) {
  __shared__ __align__(16) unsigned short Xs[64 * 256];
  __shared__ __align__(16) unsigned short Ws[64 * 256];
  __shared__ float Tr[4][32 * 33];
  const int ib = blockIdx.x, mat = blockIdx.y;
  const float* W = (mat == 0) ? Wq : (mat == 1) ? Wk : Wv;
  // fold softmax scale (1/sqrt(256)) and log2(e) into Q via Wq
  const float wscale = (mat == 0) ? 0.09016844005556021f : 1.0f;
  const int t = threadIdx.x;
  const int lane = t & 63, w = t >> 6;
  const int m = lane & 31, half = lane >> 5;
  const int i0 = ib * 64;
  // stage X tile 64x256 f32 -> bf16 LDS, xor-swizzled 16B chunks (32 chunks/row)
#pragma unroll
  for (int cc = 0; cc < 8; ++cc) {
    int chunk = t + 256 * cc;
    int rr = chunk >> 5, c = chunk & 31;
    const float4* src = (const float4*)(X + (size_t)(i0 + rr) * 256 + c * 8);
    float4 f0 = src[0], f1 = src[1];
    bf16x8 v;
    v[0] = (__bf16)f0.x; v[1] = (__bf16)f0.y; v[2] = (__bf16)f0.z; v[3] = (__bf16)f0.w;
    v[4] = (__bf16)f1.x; v[5] = (__bf16)f1.y; v[6] = (__bf16)f1.z; v[7] = (__bf16)f1.w;
    *(bf16x8*)&Xs[(rr * 32 + (c ^ (rr & 31))) * 8] = v;
  }
  const int wr = w >> 1, wc = w & 1;
  for (int cb = 0; cb < 4; ++cb) {
    __syncthreads();  // protect Ws (and cover X staging on first pass)
#pragma unroll
    for (int cc = 0; cc < 8; ++cc) {
      int chunk = t + 256 * cc;
      int rr = chunk >> 5, c = chunk & 31;
      const float4* src = (const float4*)(W + (size_t)(cb * 64 + rr) * 256 + c * 8);
      float4 f0 = src[0], f1 = src[1];
      bf16x8 v;
      v[0] = (__bf16)(f0.x * wscale); v[1] = (__bf16)(f0.y * wscale);
      v[2] = (__bf16)(f0.z * wscale); v[3] = (__bf16)(f0.w * wscale);
      v[4] = (__bf16)(f1.x * wscale); v[5] = (__bf16)(f1.y * wscale);
      v[6] = (__bf16)(f1.z * wscale); v[7] = (__bf16)(f1.w * wscale);
      *(bf16x8*)&Ws[(rr * 32 + (c ^ (rr & 31))) * 8] = v;
    }
    __syncthreads();
    f32x16 acc = {};
    const int ar = 32 * wr + m;
    const int br = 32 * wc + m;
#pragma unroll
    for (int st = 0; st < 16; ++st) {
      int kc = st * 2 + half;
      bf16x8 a = *(const bf16x8*)&Xs[(ar * 32 + (kc ^ (ar & 31))) * 8];
      bf16x8 b = *(const bf16x8*)&Ws[(br * 32 + (kc ^ (br & 31))) * 8];
      acc = MFMA32(a, b, acc);
    }
    if (mat < 2) {
      unsigned short* O = mat ? Kb : Qs;
#pragma unroll
      for (int r = 0; r < 16; ++r) {
        int row = i0 + 32 * wr + (r & 3) + 8 * (r >> 2) + 4 * half;
        int col = cb * 64 + 32 * wc + m;
        O[(size_t)row * DM + col] = f2bf_bits(acc[r]);
      }
    } else {
      // V: transpose 32x32 tile through wave-private LDS, store Vt[d][n] coalesced
      float* T = Tr[w];
#pragma unroll
      for (int r = 0; r < 16; ++r) {
        int rl = (r & 3) + 8 * (r >> 2) + 4 * half;
        T[m * 33 + rl] = acc[r];  // T[d_local][n_local]
      }
      asm volatile("s_waitcnt lgkmcnt(0)" ::: "memory");
#pragma unroll
      for (int q = 0; q < 16; ++q) {
        int dl = 2 * q + half;
        float val = T[dl * 33 + m];
        Vt[(size_t)(cb * 64 + 32 * wc + dl) * NT + i0 + 32 * wr + m] = f2bf_bits(val);
      }
      asm volatile("s_waitcnt lgkmcnt(0)" ::: "memory");
    }
  }
}

// ---------------------------------------------------------------------------
// Kernel 2: flash attention, causal, with post-softmax dropout (p=0.5 -> x2).
// BM=128 rows/block (4 waves x 32 rows), BN=64, D=256, exp2 domain.
// grid (64 row-blocks, up to 16 segments of 512 columns). Each workgroup
// writes segment partials (m, l, bf16 acc) for a later combine pass.
// ---------------------------------------------------------------------------
__global__ __launch_bounds__(256, 1) void flash_kernel(
    const unsigned short* __restrict__ Qs, const unsigned short* __restrict__ Kg,
    const unsigned short* __restrict__ Vtg, const void* __restrict__ mask,
    const int* __restrict__ flagp, float* __restrict__ ml_out,
    unsigned short* __restrict__ acc_out) {
  __shared__ __align__(16) unsigned short Ksh[64 * 256];   // K rows, swizzled
  __shared__ __align__(16) unsigned short Vsh[256 * 64];   // V^T rows, swizzled
  __shared__ __align__(16) unsigned short Psh[4 * 32 * 64];// per-wave P tiles
  const int ib = blockIdx.x;
  const int seg = blockIdx.y;
  const int jb_end = 2 * (ib + 1);
  const int jb0 = seg * 8;
  if (jb0 >= jb_end) return;
  const int jb1 = (jb0 + 8 < jb_end) ? jb0 + 8 : jb_end;
  const int t = threadIdx.x, lane = t & 63, w = t >> 6;
  const int m = lane & 31, half = lane >> 5;
  const int i0 = ib * 128, rw0 = i0 + 32 * w;
  const int mode = *flagp;

  int rowid[16];
#pragma unroll
  for (int r = 0; r < 16; ++r) rowid[r] = (r & 3) + 8 * (r >> 2) + 4 * half;

  // Q A-fragments, register resident (32 rows x 256 k per wave)
  bf16x8 qf[16];
  {
    const unsigned short* q = Qs + (size_t)(rw0 + m) * DM + half * 8;
#pragma unroll
    for (int k = 0; k < 16; ++k) qf[k] = *(const bf16x8*)(q + k * 16);
  }
  f32x16 oacc[8] = {};
  float mrun[16], lrun[16];
#pragma unroll
  for (int r = 0; r < 16; ++r) { mrun[r] = -1e30f; lrun[r] = 0.f; }

  for (int jb = jb0; jb < jb1; ++jb) {
    const int j64 = jb * 64;
    // stage K tile (64x256, 32 chunks/row) and Vt tile (256x64, 8 chunks/row);
    // xor-swizzle applied on the *global* address so LDS side stays contiguous.
#pragma unroll
    for (int q = 0; q < 8; ++q) {
      int chunk = w * 512 + q * 64 + lane;
      int row = chunk >> 5, slot = chunk & 31;
      int gc = slot ^ (row & 31);
      gload_lds16(Kg + (size_t)(j64 + row) * DM + gc * 8, Ksh + (size_t)chunk * 8);
    }
#pragma unroll
    for (int q = 0; q < 8; ++q) {
      int chunk = w * 512 + q * 64 + lane;
      int d = chunk >> 3, slot = chunk & 7;
      int gj = slot ^ (d & 7);
      gload_lds16(Vtg + (size_t)d * NT + j64 + gj * 8, Vsh + (size_t)chunk * 8);
    }
    __syncthreads();
    if (j64 <= rw0 + 31) {  // wave has at least one unmasked column here
      // dropout multipliers for this wave's 32x64 S tile, loaded in C-layout
      float dmul[2][16];
      if (mode == 0) {
        const unsigned char* mk = (const unsigned char*)mask;
#pragma unroll
        for (int t2 = 0; t2 < 2; ++t2)
#pragma unroll
          for (int r = 0; r < 16; ++r)
            dmul[t2][r] = mk[(size_t)(rw0 + rowid[r]) * NT + j64 + 32 * t2 + m] ? 2.0f : 0.0f;
      } else if (mode == 1) {
        const int* mk = (const int*)mask;
#pragma unroll
        for (int t2 = 0; t2 < 2; ++t2)
#pragma unroll
          for (int r = 0; r < 16; ++r)
            dmul[t2][r] = mk[(size_t)(rw0 + rowid[r]) * NT + j64 + 32 * t2 + m] ? 2.0f : 0.0f;
      } else {
        const float* mk = (const float*)mask;
#pragma unroll
        for (int t2 = 0; t2 < 2; ++t2)
#pragma unroll
          for (int r = 0; r < 16; ++r)
            dmul[t2][r] = (mk[(size_t)(rw0 + rowid[r]) * NT + j64 + 32 * t2 + m] != 0.f) ? 2.0f : 0.0f;
      }
      // S = Q K^T (already in log2 domain via Q pre-scale)
      f32x16 s0 = {}, s1 = {};
#pragma unroll
      for (int st = 0; st < 16; ++st) {
        int kc = st * 2 + half;
        bf16x8 b0 = *(const bf16x8*)&Ksh[(m * 32 + (kc ^ m)) * 8];
        bf16x8 b1 = *(const bf16x8*)&Ksh[((32 + m) * 32 + (kc ^ m)) * 8];
        s0 = MFMA32(qf[st], b0, s0);
        s1 = MFMA32(qf[st], b1, s1);
      }
      // causal mask (only diagonal-adjacent blocks need it)
      if (j64 + 63 > rw0) {
#pragma unroll
        for (int r = 0; r < 16; ++r) {
          int row = rw0 + rowid[r];
          if (j64 + m > row) s0[r] = NEG_INF;
          if (j64 + 32 + m > row) s1[r] = NEG_INF;
        }
      }
      // row max over 64 cols (rows live within one 32-lane half)
      float mx[16];
#pragma unroll
      for (int r = 0; r < 16; ++r) mx[r] = fmaxf(s0[r], s1[r]);
#pragma unroll
      for (int off = 1; off <= 16; off <<= 1)
#pragma unroll
        for (int r = 0; r < 16; ++r) mx[r] = fmaxf(mx[r], __shfl_xor(mx[r], off));
      float alpha[16];
#pragma unroll
      for (int r = 0; r < 16; ++r) {
        float mn = fmaxf(mrun[r], mx[r]);
        alpha[r] = exp2_fast(mrun[r] - mn);
        mrun[r] = mn;
      }
#pragma unroll
      for (int r = 0; r < 16; ++r) {
        s0[r] = exp2_fast(s0[r] - mrun[r]);
        s1[r] = exp2_fast(s1[r] - mrun[r]);
      }
      float rs[16];
#pragma unroll
      for (int r = 0; r < 16; ++r) rs[r] = s0[r] + s1[r];
#pragma unroll
      for (int off = 1; off <= 16; off <<= 1)
#pragma unroll
        for (int r = 0; r < 16; ++r) rs[r] += __shfl_xor(rs[r], off);
#pragma unroll
      for (int r = 0; r < 16; ++r) lrun[r] = lrun[r] * alpha[r] + rs[r];
#pragma unroll
      for (int ct = 0; ct < 8; ++ct)
#pragma unroll
        for (int r = 0; r < 16; ++r) oacc[ct][r] *= alpha[r];
      // apply dropout, write P to wave-private LDS (swizzled A-layout source)
      unsigned short* P = &Psh[w * 2048];
#pragma unroll
      for (int r = 0; r < 16; ++r) {
        int row = rowid[r];
        int c0 = m, c1 = 32 + m;
        P[row * 64 + (((c0 >> 3) ^ (row & 7)) << 3) + (c0 & 7)] = f2bf_bits(s0[r] * dmul[0][r]);
        P[row * 64 + (((c1 >> 3) ^ (row & 7)) << 3) + (c1 & 7)] = f2bf_bits(s1[r] * dmul[1][r]);
      }
      asm volatile("s_waitcnt lgkmcnt(0)" ::: "memory");
      bf16x8 pf[4];
#pragma unroll
      for (int ks = 0; ks < 4; ++ks) {
        int kc = ks * 2 + half;
        pf[ks] = *(const bf16x8*)&P[m * 64 + ((kc ^ (m & 7)) << 3)];
      }
      // O += P @ V  (B operand = Vt rows, contiguous k-runs)
#pragma unroll
      for (int ct = 0; ct < 8; ++ct) {
        int d = ct * 32 + m;
#pragma unroll
        for (int ks = 0; ks < 4; ++ks) {
          int kc = ks * 2 + half;
          bf16x8 b = *(const bf16x8*)&Vsh[d * 64 + ((kc ^ (d & 7)) << 3)];
          oacc[ct] = MFMA32(pf[ks], b, oacc[ct]);
        }
      }
    }
    __syncthreads();  // staging of next tile must not overwrite live K/V
  }
  // write segment partials
  const int a_ = ib >> 2, r_ = ib & 3;
  const int g = 2 * a_ * (a_ + 1) + r_ * (a_ + 1) + seg;
  float* mlb = ml_out + ((size_t)g * 128 + 32 * w) * 2;
#pragma unroll
  for (int r = 0; r < 16; ++r) {
    if (m == r) {
      mlb[rowid[r] * 2 + 0] = mrun[r];
      mlb[rowid[r] * 2 + 1] = lrun[r];
    }
  }
  unsigned short* ab = acc_out + ((size_t)g * 128 + 32 * w) * DM;
#pragma unroll
  for (int ct = 0; ct < 8; ++ct)
#pragma unroll
    for (int r = 0; r < 16; ++r)
      ab[(size_t)rowid[r] * DM + ct * 32 + m] = f2bf_bits(oacc[ct][r]);
}

// ---------------------------------------------------------------------------
// Kernel 3: combine segment partials. O = sum_s w_s*acc_s / sum_s w_s*l_s,
// w_s = 2^(m_s - M). grid 256 blocks x 256 thr; thread = (row, 32-col group).
// ---------------------------------------------------------------------------
__global__ __launch_bounds__(256) void combine_kernel(
    const float* __restrict__ ml, const unsigned short* __restrict__ pacc,
    float* __restrict__ out) {
  const int t = threadIdx.x;
  const int row = blockIdx.x * 32 + (t >> 3);
  const int cg = (t & 7) * 32;
  const int i = row >> 7, rib = row & 127;
  const int a = i >> 2, r = i & 3;
  const int g0 = 2 * a * (a + 1) + r * (a + 1);
  const int ns = (i + 4) >> 2;
  float M = -1e30f;
  for (int s = 0; s < ns; ++s) M = fmaxf(M, ml[((size_t)(g0 + s) * 128 + rib) * 2]);
  float Wd = 0.f;
  float acc[32];
#pragma unroll
  for (int j = 0; j < 32; ++j) acc[j] = 0.f;
  for (int s = 0; s < ns; ++s) {
    const float* mls = ml + ((size_t)(g0 + s) * 128 + rib) * 2;
    float wv = exp2_fast(mls[0] - M);
    Wd += wv * mls[1];
    const unsigned short* pa = pacc + ((size_t)(g0 + s) * 128 + rib) * DM + cg;
#pragma unroll
    for (int v4 = 0; v4 < 4; ++v4) {
      bf16x8 b = *(const bf16x8*)(pa + v4 * 8);
#pragma unroll
      for (int j = 0; j < 8; ++j) acc[v4 * 8 + j] += wv * (float)b[j];
    }
  }
  float inv = 1.0f / Wd;
#pragma unroll
  for (int j = 0; j < 32; ++j) out[(size_t)row * DM + cg + j] = acc[j] * inv;
}

// ---------------------------------------------------------------------------
extern "C" void kernel_launch(void* const* d_in, const int* in_sizes, int n_in,
                              void* d_out, int out_size, void* d_ws, size_t ws_size,
                              hipStream_t stream) {
  const float* X  = (const float*)d_in[0];
  const float* Wq = (const float*)d_in[1];
  const float* Wk = (const float*)d_in[2];
  const float* Wv = (const float*)d_in[3];
  const void* mask = d_in[4];
  float* out = (float*)d_out;

  char* ws = (char*)d_ws;
  int* flag = (int*)ws;
  unsigned short* Qs = (unsigned short*)(ws + 4096);
  unsigned short* Kb = Qs + (size_t)NT * DM;
  unsigned short* Vt = Kb + (size_t)NT * DM;
  float* ml = (float*)(Vt + (size_t)NT * DM);
  unsigned short* pacc = (unsigned short*)(ml + (size_t)544 * 128 * 2);
  // total ws use: 4096 + 3*4MiB + 544KiB + 34MiB ~= 47.3 MiB

  detect_kernel<<<1, 256, 0, stream>>>((const unsigned int*)mask, flag);
  proj_kernel<<<dim3(128, 3), 256, 0, stream>>>(X, Wq, Wk, Wv, Qs, Kb, Vt);
  flash_kernel<<<dim3(64, 16), 256, 0, stream>>>(Qs, Kb, Vt, mask, flag, ml, pacc);
  combine_kernel<<<256, 256, 0, stream>>>(ml, pacc, out);
}

// Round 2
// 587.659 us; speedup vs baseline: 1.3513x; 1.3513x over previous
//
#include <hip/hip_runtime.h>

// Problem constants (N=8192 tokens, D=256 model dim, dropout p=0.5 -> keep scale 2.0)
#define NT 8192
#define DM 256

typedef float f32x16 __attribute__((ext_vector_type(16)));
typedef float f32x4 __attribute__((ext_vector_type(4)));
typedef __bf16 bf16x8 __attribute__((ext_vector_type(8)));

#define MFMA32(a, b, c) __builtin_amdgcn_mfma_f32_32x32x16_bf16((a), (b), (c), 0, 0, 0)
#define MFMA16(a, b, c) __builtin_amdgcn_mfma_f32_16x16x32_bf16((a), (b), (c), 0, 0, 0)
#define NEG_INF (-__builtin_inff())

static __device__ __forceinline__ unsigned short f2bf_bits(float f) {
  return __builtin_bit_cast(unsigned short, (__bf16)f);
}
static __device__ __forceinline__ float exp2_fast(float x) {
  return __builtin_amdgcn_exp2f(x);
}
// async global->LDS, 16B per lane. LDS dest is wave-uniform base + lane*16.
static __device__ __forceinline__ void gload_lds16(const void* g, void* l) {
  __builtin_amdgcn_global_load_lds(
      (const __attribute__((address_space(1))) unsigned int*)g,
      (__attribute__((address_space(3))) unsigned int*)l, 16, 0, 0);
}

// ---------------------------------------------------------------------------
// Kernel 0: classify drop_mask storage. 1 = int32 {0,1}, 2 = float32 {0,1.0f},
// 0 = uint8 bytes. Scans first 256 dwords.
// ---------------------------------------------------------------------------
__global__ void detect_kernel(const unsigned int* __restrict__ m, int* __restrict__ flag) {
  __shared__ int s01, sf;
  int t = threadIdx.x;
  if (t == 0) { s01 = 1; sf = 1; }
  __syncthreads();
  unsigned int v = m[t];
  if (v > 1u) atomicAnd(&s01, 0);
  if (v != 0u && v != 0x3F800000u) atomicAnd(&sf, 0);
  __syncthreads();
  if (t == 0) *flag = s01 ? 1 : (sf ? 2 : 0);
}

// ---------------------------------------------------------------------------
// Kernel 1: QKV projection. X[8192][256] f32, W[256][256] f32 (torch layout,
// out = X @ W^T). Outputs bf16: Qs (pre-scaled by log2(e)/16), K, and V stored
// transposed Vt[256][8192].
// grid (128 row-blocks, 3 mats), block 256.
// ---------------------------------------------------------------------------
__global__ __launch_bounds__(256) void proj_kernel(
    const float* __restrict__ X, const float* __restrict__ Wq,
    const float* __restrict__ Wk, const float* __restrict__ Wv,
    unsigned short* __restrict__ Qs, unsigned short* __restrict__ Kb,
    unsigned short* __restrict__ Vt) {
  __shared__ __align__(16) unsigned short Xs[64 * 256];
  __shared__ __align__(16) unsigned short Ws[64 * 256];
  __shared__ float Tr[4][32 * 33];
  const int ib = blockIdx.x, mat = blockIdx.y;
  const float* W = (mat == 0) ? Wq : (mat == 1) ? Wk : Wv;
  // fold softmax scale (1/sqrt(256)) and log2(e) into Q via Wq
  const float wscale = (mat == 0) ? 0.09016844005556021f : 1.0f;
  const int t = threadIdx.x;
  const int lane = t & 63, w = t >> 6;
  const int m = lane & 31, half = lane >> 5;
  const int i0 = ib * 64;
  // stage X tile 64x256 f32 -> bf16 LDS, xor-swizzled 16B chunks (32 chunks/row)
#pragma unroll
  for (int cc = 0; cc < 8; ++cc) {
    int chunk = t + 256 * cc;
    int rr = chunk >> 5, c = chunk & 31;
    const float4* src = (const float4*)(X + (size_t)(i0 + rr) * 256 + c * 8);
    float4 f0 = src[0], f1 = src[1];
    bf16x8 v;
    v[0] = (__bf16)f0.x; v[1] = (__bf16)f0.y; v[2] = (__bf16)f0.z; v[3] = (__bf16)f0.w;
    v[4] = (__bf16)f1.x; v[5] = (__bf16)f1.y; v[6] = (__bf16)f1.z; v[7] = (__bf16)f1.w;
    *(bf16x8*)&Xs[(rr * 32 + (c ^ (rr & 31))) * 8] = v;
  }
  const int wr = w >> 1, wc = w & 1;
  for (int cb = 0; cb < 4; ++cb) {
    __syncthreads();  // protect Ws (and cover X staging on first pass)
#pragma unroll
    for (int cc = 0; cc < 8; ++cc) {
      int chunk = t + 256 * cc;
      int rr = chunk >> 5, c = chunk & 31;
      const float4* src = (const float4*)(W + (size_t)(cb * 64 + rr) * 256 + c * 8);
      float4 f0 = src[0], f1 = src[1];
      bf16x8 v;
      v[0] = (__bf16)(f0.x * wscale); v[1] = (__bf16)(f0.y * wscale);
      v[2] = (__bf16)(f0.z * wscale); v[3] = (__bf16)(f0.w * wscale);
      v[4] = (__bf16)(f1.x * wscale); v[5] = (__bf16)(f1.y * wscale);
      v[6] = (__bf16)(f1.z * wscale); v[7] = (__bf16)(f1.w * wscale);
      *(bf16x8*)&Ws[(rr * 32 + (c ^ (rr & 31))) * 8] = v;
    }
    __syncthreads();
    f32x16 acc = {};
    const int ar = 32 * wr + m;
    const int br = 32 * wc + m;
#pragma unroll
    for (int st = 0; st < 16; ++st) {
      int kc = st * 2 + half;
      bf16x8 a = *(const bf16x8*)&Xs[(ar * 32 + (kc ^ (ar & 31))) * 8];
      bf16x8 b = *(const bf16x8*)&Ws[(br * 32 + (kc ^ (br & 31))) * 8];
      acc = MFMA32(a, b, acc);
    }
    if (mat < 2) {
      unsigned short* O = mat ? Kb : Qs;
#pragma unroll
      for (int r = 0; r < 16; ++r) {
        int row = i0 + 32 * wr + (r & 3) + 8 * (r >> 2) + 4 * half;
        int col = cb * 64 + 32 * wc + m;
        O[(size_t)row * DM + col] = f2bf_bits(acc[r]);
      }
    } else {
      // V: transpose 32x32 tile through wave-private LDS, store Vt[d][n] coalesced
      float* T = Tr[w];
#pragma unroll
      for (int r = 0; r < 16; ++r) {
        int rl = (r & 3) + 8 * (r >> 2) + 4 * half;
        T[m * 33 + rl] = acc[r];  // T[d_local][n_local]
      }
      asm volatile("s_waitcnt lgkmcnt(0)" ::: "memory");
#pragma unroll
      for (int q = 0; q < 16; ++q) {
        int dl = 2 * q + half;
        float val = T[dl * 33 + m];
        Vt[(size_t)(cb * 64 + 32 * wc + dl) * NT + i0 + 32 * wr + m] = f2bf_bits(val);
      }
      asm volatile("s_waitcnt lgkmcnt(0)" ::: "memory");
    }
  }
}

// ---------------------------------------------------------------------------
// Kernel 2: flash attention, causal, post-softmax dropout (p=0.5 -> x2).
// v2: 16-row waves with 16x16x32 MFMA to kill register spills (v1: 350-reg
// live set behind a 256 cap -> ~100 MB scratch traffic, 497 us).
// BM=64 rows/block (4 waves x 16 rows), BN=64, D=256, exp2 domain.
// grid (128 row-blocks, up to 16 segments of 512 cols); 72 KiB LDS ->
// 2 blocks/CU, launch_bounds(256,2) -> 8 waves/CU.
// Lane mapping (16x16x32): m=lane&15, q=lane>>4.
//   A[m][q*8+j], B[q*8+j][m], C[q*4+reg][m].
// ---------------------------------------------------------------------------
__global__ __launch_bounds__(256, 2) void flash_kernel(
    const unsigned short* __restrict__ Qs, const unsigned short* __restrict__ Kg,
    const unsigned short* __restrict__ Vtg, const void* __restrict__ mask,
    const int* __restrict__ flagp, float* __restrict__ ml_out,
    unsigned short* __restrict__ acc_out) {
  __shared__ __align__(16) unsigned short Ksh[64 * 256];   // K rows, swizzled (32 KiB)
  __shared__ __align__(16) unsigned short Vsh[256 * 64];   // V^T rows, swizzled (32 KiB)
  __shared__ __align__(16) unsigned short Psh[4][16 * 64]; // per-wave P tiles (8 KiB)
  const int ib = blockIdx.x;
  const int seg = blockIdx.y;
  const int jb_end = ib + 1;
  const int jb0 = seg * 8;
  if (jb0 >= jb_end) return;
  const int jb1 = (jb0 + 8 < jb_end) ? jb0 + 8 : jb_end;
  const int t = threadIdx.x, lane = t & 63, w = t >> 6;
  const int m = lane & 15, q = lane >> 4;
  const int i0 = ib * 64, rw0 = i0 + 16 * w;
  const int mode = *flagp;

  // Q A-fragments, register resident (16 rows x 256 k per wave -> 32 VGPRs)
  bf16x8 qf[8];
  {
    const unsigned short* qp = Qs + (size_t)(rw0 + m) * DM + q * 8;
#pragma unroll
    for (int st = 0; st < 8; ++st) qf[st] = *(const bf16x8*)(qp + st * 32);
  }
  f32x4 oacc[16] = {};
  float mrun[4], lrun[4];
#pragma unroll
  for (int r = 0; r < 4; ++r) { mrun[r] = -1e30f; lrun[r] = 0.f; }

  for (int jb = jb0; jb < jb1; ++jb) {
    const int j64 = jb * 64;
    // stage K tile (64 rows x 256 k, 32 chunks/row) and Vt tile (256 x 64,
    // 8 chunks/row); xor-swizzle applied on the *global* address so the LDS
    // side stays wave-uniform-base + lane*16.
#pragma unroll
    for (int qq = 0; qq < 8; ++qq) {
      int chunk = w * 512 + qq * 64 + lane;
      int row = chunk >> 5, slot = chunk & 31;
      int gc = slot ^ (row & 31);
      gload_lds16(Kg + (size_t)(j64 + row) * DM + gc * 8, Ksh + (size_t)chunk * 8);
    }
#pragma unroll
    for (int qq = 0; qq < 8; ++qq) {
      int chunk = w * 512 + qq * 64 + lane;
      int d = chunk >> 3, slot = chunk & 7;
      int gj = slot ^ (d & 7);
      gload_lds16(Vtg + (size_t)d * NT + j64 + gj * 8, Vsh + (size_t)chunk * 8);
    }
    __syncthreads();
    if (j64 <= rw0 + 15) {  // wave has at least one unmasked column here
      // S = Q K^T (already in log2 domain via Q pre-scale). 4 col-blocks of 16.
      f32x4 s[4] = {};
#pragma unroll
      for (int st = 0; st < 8; ++st) {
        int kc = st * 4 + q;
#pragma unroll
        for (int ct = 0; ct < 4; ++ct) {
          int brow = ct * 16 + m;
          bf16x8 b = *(const bf16x8*)&Ksh[(brow * 32 + (kc ^ (brow & 31))) * 8];
          s[ct] = MFMA16(qf[st], b, s[ct]);
        }
      }
      // causal mask (only diagonal-adjacent blocks need it)
      if (j64 + 63 > rw0) {
#pragma unroll
        for (int ct = 0; ct < 4; ++ct)
#pragma unroll
          for (int r = 0; r < 4; ++r) {
            int grow = rw0 + q * 4 + r;
            if (j64 + ct * 16 + m > grow) s[ct][r] = NEG_INF;
          }
      }
      // row max over 64 cols (each row lives in one 16-lane group)
      float mx[4];
#pragma unroll
      for (int r = 0; r < 4; ++r)
        mx[r] = fmaxf(fmaxf(s[0][r], s[1][r]), fmaxf(s[2][r], s[3][r]));
#pragma unroll
      for (int off = 1; off <= 8; off <<= 1)
#pragma unroll
        for (int r = 0; r < 4; ++r) mx[r] = fmaxf(mx[r], __shfl_xor(mx[r], off));
      float alpha[4];
#pragma unroll
      for (int r = 0; r < 4; ++r) {
        float mn = fmaxf(mrun[r], mx[r]);
        alpha[r] = exp2_fast(mrun[r] - mn);
        mrun[r] = mn;
      }
#pragma unroll
      for (int ct = 0; ct < 4; ++ct)
#pragma unroll
        for (int r = 0; r < 4; ++r) s[ct][r] = exp2_fast(s[ct][r] - mrun[r]);
      float rs[4];
#pragma unroll
      for (int r = 0; r < 4; ++r) rs[r] = (s[0][r] + s[1][r]) + (s[2][r] + s[3][r]);
#pragma unroll
      for (int off = 1; off <= 8; off <<= 1)
#pragma unroll
        for (int r = 0; r < 4; ++r) rs[r] += __shfl_xor(rs[r], off);
#pragma unroll
      for (int r = 0; r < 4; ++r) lrun[r] = lrun[r] * alpha[r] + rs[r];
#pragma unroll
      for (int ct = 0; ct < 16; ++ct)
#pragma unroll
        for (int r = 0; r < 4; ++r) oacc[ct][r] *= alpha[r];
      // dropout multipliers (C-layout) then P -> wave-private LDS (swizzled)
      float dm[4][4];
      if (mode == 0) {
        const unsigned char* mk = (const unsigned char*)mask;
#pragma unroll
        for (int ct = 0; ct < 4; ++ct)
#pragma unroll
          for (int r = 0; r < 4; ++r)
            dm[ct][r] = mk[(size_t)(rw0 + q * 4 + r) * NT + j64 + ct * 16 + m] ? 2.0f : 0.0f;
      } else if (mode == 1) {
        const int* mk = (const int*)mask;
#pragma unroll
        for (int ct = 0; ct < 4; ++ct)
#pragma unroll
          for (int r = 0; r < 4; ++r)
            dm[ct][r] = mk[(size_t)(rw0 + q * 4 + r) * NT + j64 + ct * 16 + m] ? 2.0f : 0.0f;
      } else {
        const float* mk = (const float*)mask;
#pragma unroll
        for (int ct = 0; ct < 4; ++ct)
#pragma unroll
          for (int r = 0; r < 4; ++r)
            dm[ct][r] = (mk[(size_t)(rw0 + q * 4 + r) * NT + j64 + ct * 16 + m] != 0.f) ? 2.0f : 0.0f;
      }
      unsigned short* P = Psh[w];
#pragma unroll
      for (int ct = 0; ct < 4; ++ct)
#pragma unroll
        for (int r = 0; r < 4; ++r) {
          int row = q * 4 + r, col = ct * 16 + m;
          P[row * 64 + (((col >> 3) ^ (row & 7)) << 3) + (col & 7)] =
              f2bf_bits(s[ct][r] * dm[ct][r]);
        }
      asm volatile("s_waitcnt lgkmcnt(0)" ::: "memory");
      // P A-frags (K=64 -> 2 MFMA k-steps)
      bf16x8 pf[2];
#pragma unroll
      for (int ks = 0; ks < 2; ++ks) {
        int kc = ks * 4 + q;
        pf[ks] = *(const bf16x8*)&P[m * 64 + ((kc ^ (m & 7)) << 3)];
      }
      // O += P @ V  (B operand = Vt rows, contiguous j-runs)
#pragma unroll
      for (int ct = 0; ct < 16; ++ct) {
        int vrow = ct * 16 + m;
#pragma unroll
        for (int ks = 0; ks < 2; ++ks) {
          int kc = ks * 4 + q;
          bf16x8 b = *(const bf16x8*)&Vsh[(vrow * 8 + (kc ^ (vrow & 7))) * 8];
          oacc[ct] = MFMA16(pf[ks], b, oacc[ct]);
        }
      }
    }
    __syncthreads();  // staging of next tile must not overwrite live K/V
  }
  // write segment partials. g = segment slot for (ib, seg).
  const int a_ = ib >> 3, r_ = ib & 7;
  const int g = 4 * a_ * (a_ + 1) + r_ * (a_ + 1) + seg;
  float* mlb = ml_out + ((size_t)g * 64 + 16 * w) * 2;
  if (m == 0) {
#pragma unroll
    for (int r = 0; r < 4; ++r) {
      mlb[(q * 4 + r) * 2 + 0] = mrun[r];
      mlb[(q * 4 + r) * 2 + 1] = lrun[r];
    }
  }
  unsigned short* ab = acc_out + ((size_t)g * 64 + 16 * w) * DM;
#pragma unroll
  for (int ct = 0; ct < 16; ++ct)
#pragma unroll
    for (int r = 0; r < 4; ++r)
      ab[(size_t)(q * 4 + r) * DM + ct * 16 + m] = f2bf_bits(oacc[ct][r]);
}

// ---------------------------------------------------------------------------
// Kernel 3: combine segment partials. O = sum_s w_s*acc_s / sum_s w_s*l_s,
// w_s = 2^(m_s - M). grid 256 blocks x 256 thr; thread = (row, 32-col group).
// ---------------------------------------------------------------------------
__global__ __launch_bounds__(256) void combine_kernel(
    const float* __restrict__ ml, const unsigned short* __restrict__ pacc,
    float* __restrict__ out) {
  const int t = threadIdx.x;
  const int row = blockIdx.x * 32 + (t >> 3);
  const int cg = (t & 7) * 32;
  const int ib = row >> 6, rib = row & 63;
  const int a = ib >> 3, r = ib & 7;
  const int g0 = 4 * a * (a + 1) + r * (a + 1);
  const int ns = a + 1;
  float M = -1e30f;
  for (int s = 0; s < ns; ++s) M = fmaxf(M, ml[((size_t)(g0 + s) * 64 + rib) * 2]);
  float Wd = 0.f;
  float acc[32];
#pragma unroll
  for (int j = 0; j < 32; ++j) acc[j] = 0.f;
  for (int s = 0; s < ns; ++s) {
    const float* mls = ml + ((size_t)(g0 + s) * 64 + rib) * 2;
    float wv = exp2_fast(mls[0] - M);
    Wd += wv * mls[1];
    const unsigned short* pa = pacc + ((size_t)(g0 + s) * 64 + rib) * DM + cg;
#pragma unroll
    for (int v4 = 0; v4 < 4; ++v4) {
      bf16x8 b = *(const bf16x8*)(pa + v4 * 8);
#pragma unroll
      for (int j = 0; j < 8; ++j) acc[v4 * 8 + j] += wv * (float)b[j];
    }
  }
  float inv = 1.0f / Wd;
#pragma unroll
  for (int j = 0; j < 32; ++j) out[(size_t)row * DM + cg + j] = acc[j] * inv;
}

// ---------------------------------------------------------------------------
extern "C" void kernel_launch(void* const* d_in, const int* in_sizes, int n_in,
                              void* d_out, int out_size, void* d_ws, size_t ws_size,
                              hipStream_t stream) {
  const float* X  = (const float*)d_in[0];
  const float* Wq = (const float*)d_in[1];
  const float* Wk = (const float*)d_in[2];
  const float* Wv = (const float*)d_in[3];
  const void* mask = d_in[4];
  float* out = (float*)d_out;

  char* ws = (char*)d_ws;
  int* flag = (int*)ws;
  unsigned short* Qs = (unsigned short*)(ws + 4096);
  unsigned short* Kb = Qs + (size_t)NT * DM;
  unsigned short* Vt = Kb + (size_t)NT * DM;
  float* ml = (float*)(Vt + (size_t)NT * DM);
  unsigned short* pacc = (unsigned short*)(ml + (size_t)1088 * 64 * 2);
  // total ws use: 4096 + 3*4MiB + 544KiB + 34MiB ~= 47.3 MiB

  detect_kernel<<<1, 256, 0, stream>>>((const unsigned int*)mask, flag);
  proj_kernel<<<dim3(128, 3), 256, 0, stream>>>(X, Wq, Wk, Wv, Qs, Kb, Vt);
  flash_kernel<<<dim3(128, 16), 256, 0, stream>>>(Qs, Kb, Vt, mask, flag, ml, pacc);
  combine_kernel<<<256, 256, 0, stream>>>(ml, pacc, out);
}

// Round 3
// 527.443 us; speedup vs baseline: 1.5055x; 1.1142x over previous
//
#include <hip/hip_runtime.h>

// Problem constants (N=8192 tokens, D=256 model dim, dropout p=0.5 -> keep scale 2.0)
#define NT 8192
#define DM 256

typedef float f32x16 __attribute__((ext_vector_type(16)));
typedef float f32x4 __attribute__((ext_vector_type(4)));
typedef __bf16 bf16x8 __attribute__((ext_vector_type(8)));

#define MFMA32(a, b, c) __builtin_amdgcn_mfma_f32_32x32x16_bf16((a), (b), (c), 0, 0, 0)
#define MFMA16(a, b, c) __builtin_amdgcn_mfma_f32_16x16x32_bf16((a), (b), (c), 0, 0, 0)
#define NEG_INF (-__builtin_inff())

static __device__ __forceinline__ unsigned short f2bf_bits(float f) {
  return __builtin_bit_cast(unsigned short, (__bf16)f);
}
static __device__ __forceinline__ float exp2_fast(float x) {
  return __builtin_amdgcn_exp2f(x);
}
// async global->LDS, 16B per lane. LDS dest is wave-uniform base + lane*16.
static __device__ __forceinline__ void gload_lds16(const void* g, void* l) {
  __builtin_amdgcn_global_load_lds(
      (const __attribute__((address_space(1))) unsigned int*)g,
      (__attribute__((address_space(3))) unsigned int*)l, 16, 0, 0);
}

// ---------------------------------------------------------------------------
// Kernel 0: classify drop_mask storage. 1 = int32 {0,1}, 2 = float32 {0,1.0f},
// 0 = uint8 bytes. Scans first 256 dwords. (Only element size matters below.)
// ---------------------------------------------------------------------------
__global__ void detect_kernel(const unsigned int* __restrict__ m, int* __restrict__ flag) {
  __shared__ int s01, sf;
  int t = threadIdx.x;
  if (t == 0) { s01 = 1; sf = 1; }
  __syncthreads();
  unsigned int v = m[t];
  if (v > 1u) atomicAnd(&s01, 0);
  if (v != 0u && v != 0x3F800000u) atomicAnd(&sf, 0);
  __syncthreads();
  if (t == 0) *flag = s01 ? 1 : (sf ? 2 : 0);
}

// ---------------------------------------------------------------------------
// Kernel 0b: compress drop_mask (lower triangle only) into a bitmask,
// bm[i] = 8192 bits (128 u64 words). Pure streaming, ballot-based.
// One wave per row, rows interleaved across blocks for balance.
// ---------------------------------------------------------------------------
__global__ __launch_bounds__(256) void maskpack_kernel(
    const void* __restrict__ mask, const int* __restrict__ flagp,
    unsigned long long* __restrict__ bm) {
  const int t = threadIdx.x, lane = t & 63, w = t >> 6;
  const int r = blockIdx.x + (w << 11);  // grid 2048 -> rows r, r+2048, ...
  const int mode = *flagp;               // 0 = 1-byte elements, else 4-byte
  const int jmax = ((r >> 6) + 1) << 6;  // cover cols 0..r (round up to 64)
  unsigned long long* out = bm + (size_t)r * 128;
  if (mode == 0) {
    const unsigned char* mk = (const unsigned char*)mask + (size_t)r * NT;
    for (int j = 0; j < jmax; j += 64) {
      unsigned long long b = __ballot(mk[j + lane] != 0);
      if (lane == 0) out[j >> 6] = b;
    }
  } else {
    const unsigned int* mk = (const unsigned int*)mask + (size_t)r * NT;
    for (int j = 0; j < jmax; j += 64) {
      unsigned long long b = __ballot(mk[j + lane] != 0u);
      if (lane == 0) out[j >> 6] = b;
    }
  }
}

// ---------------------------------------------------------------------------
// Kernel 1: QKV projection. X[8192][256] f32, W[256][256] f32 (torch layout,
// out = X @ W^T). Outputs bf16: Qs (pre-scaled by log2(e)/16), K, and V stored
// transposed Vt[256][8192]. grid (128 row-blocks, 3 mats), block 256.
// ---------------------------------------------------------------------------
__global__ __launch_bounds__(256) void proj_kernel(
    const float* __restrict__ X, const float* __restrict__ Wq,
    const float* __restrict__ Wk, const float* __restrict__ Wv,
    unsigned short* __restrict__ Qs, unsigned short* __restrict__ Kb,
    unsigned short* __restrict__ Vt) {
  __shared__ __align__(16) unsigned short Xs[64 * 256];
  __shared__ __align__(16) unsigned short Ws[64 * 256];
  __shared__ float Tr[4][32 * 33];
  const int ib = blockIdx.x, mat = blockIdx.y;
  const float* W = (mat == 0) ? Wq : (mat == 1) ? Wk : Wv;
  // fold softmax scale (1/sqrt(256)) and log2(e) into Q via Wq
  const float wscale = (mat == 0) ? 0.09016844005556021f : 1.0f;
  const int t = threadIdx.x;
  const int lane = t & 63, w = t >> 6;
  const int m = lane & 31, half = lane >> 5;
  const int i0 = ib * 64;
#pragma unroll
  for (int cc = 0; cc < 8; ++cc) {
    int chunk = t + 256 * cc;
    int rr = chunk >> 5, c = chunk & 31;
    const float4* src = (const float4*)(X + (size_t)(i0 + rr) * 256 + c * 8);
    float4 f0 = src[0], f1 = src[1];
    bf16x8 v;
    v[0] = (__bf16)f0.x; v[1] = (__bf16)f0.y; v[2] = (__bf16)f0.z; v[3] = (__bf16)f0.w;
    v[4] = (__bf16)f1.x; v[5] = (__bf16)f1.y; v[6] = (__bf16)f1.z; v[7] = (__bf16)f1.w;
    *(bf16x8*)&Xs[(rr * 32 + (c ^ (rr & 31))) * 8] = v;
  }
  const int wr = w >> 1, wc = w & 1;
  for (int cb = 0; cb < 4; ++cb) {
    __syncthreads();
#pragma unroll
    for (int cc = 0; cc < 8; ++cc) {
      int chunk = t + 256 * cc;
      int rr = chunk >> 5, c = chunk & 31;
      const float4* src = (const float4*)(W + (size_t)(cb * 64 + rr) * 256 + c * 8);
      float4 f0 = src[0], f1 = src[1];
      bf16x8 v;
      v[0] = (__bf16)(f0.x * wscale); v[1] = (__bf16)(f0.y * wscale);
      v[2] = (__bf16)(f0.z * wscale); v[3] = (__bf16)(f0.w * wscale);
      v[4] = (__bf16)(f1.x * wscale); v[5] = (__bf16)(f1.y * wscale);
      v[6] = (__bf16)(f1.z * wscale); v[7] = (__bf16)(f1.w * wscale);
      *(bf16x8*)&Ws[(rr * 32 + (c ^ (rr & 31))) * 8] = v;
    }
    __syncthreads();
    f32x16 acc = {};
    const int ar = 32 * wr + m;
    const int br = 32 * wc + m;
#pragma unroll
    for (int st = 0; st < 16; ++st) {
      int kc = st * 2 + half;
      bf16x8 a = *(const bf16x8*)&Xs[(ar * 32 + (kc ^ (ar & 31))) * 8];
      bf16x8 b = *(const bf16x8*)&Ws[(br * 32 + (kc ^ (br & 31))) * 8];
      acc = MFMA32(a, b, acc);
    }
    if (mat < 2) {
      unsigned short* O = mat ? Kb : Qs;
#pragma unroll
      for (int r = 0; r < 16; ++r) {
        int row = i0 + 32 * wr + (r & 3) + 8 * (r >> 2) + 4 * half;
        int col = cb * 64 + 32 * wc + m;
        O[(size_t)row * DM + col] = f2bf_bits(acc[r]);
      }
    } else {
      float* T = Tr[w];
#pragma unroll
      for (int r = 0; r < 16; ++r) {
        int rl = (r & 3) + 8 * (r >> 2) + 4 * half;
        T[m * 33 + rl] = acc[r];
      }
      asm volatile("s_waitcnt lgkmcnt(0)" ::: "memory");
#pragma unroll
      for (int q = 0; q < 16; ++q) {
        int dl = 2 * q + half;
        float val = T[dl * 33 + m];
        Vt[(size_t)(cb * 64 + 32 * wc + dl) * NT + i0 + 32 * wr + m] = f2bf_bits(val);
      }
      asm volatile("s_waitcnt lgkmcnt(0)" ::: "memory");
    }
  }
}

// ---------------------------------------------------------------------------
// Kernel 2: flash attention, causal, post-softmax dropout (p=0.5 -> x2).
// v3: transposed MFMA layout (S^T = K Q^T, O^T = V^T P^T) so each lane owns
// exactly one query row: scalar m/l state, 2-shuffle row reductions, per-lane
// bitmask dropout, contiguous 8B output stores. BN=32 -> 36 KiB LDS,
// 3 blocks/CU at launch_bounds(256,3).
// Lane mapping (16x16x32): m=lane&15, q=lane>>4.
//   A[m][q*8+j], B[q*8+j][m], D[q*4+reg][m].
// ---------------------------------------------------------------------------
__global__ __launch_bounds__(256, 3) void flash_kernel(
    const unsigned short* __restrict__ Qs, const unsigned short* __restrict__ Kg,
    const unsigned short* __restrict__ Vtg, const unsigned int* __restrict__ bm,
    float* __restrict__ ml_out, unsigned short* __restrict__ acc_out) {
  __shared__ __align__(16) unsigned short Ksh[32 * 256];   // 16 KiB, swizzled
  __shared__ __align__(16) unsigned short Vsh[256 * 32];   // 16 KiB, swizzled
  __shared__ __align__(16) unsigned short Psh[4][16 * 32]; // 4 KiB, per-wave
  const int ib = blockIdx.x;
  const int seg = blockIdx.y;
  const int jb_end = 2 * (ib + 1);   // 32-col tiles
  const int jb0 = seg * 16;
  if (jb0 >= jb_end) return;
  const int jb1 = (jb0 + 16 < jb_end) ? jb0 + 16 : jb_end;
  const int t = threadIdx.x, lane = t & 63, w = t >> 6;
  const int m = lane & 15, q = lane >> 4;
  const int i0 = ib * 64, rw0 = i0 + 16 * w;
  const int myrow = rw0 + m;

  // Q B-fragments, register resident (16 rows x 256 k per wave -> 32 VGPRs)
  bf16x8 qf[8];
  {
    const unsigned short* qp = Qs + (size_t)myrow * DM + q * 8;
#pragma unroll
    for (int st = 0; st < 8; ++st) qf[st] = *(const bf16x8*)(qp + st * 32);
  }
  f32x4 oacc[16] = {};          // O^T: d = ct*16 + q*4 + r, row i = myrow
  float mrun = -1e30f, lrun = 0.f;

  for (int jb = jb0; jb < jb1; ++jb) {
    const int j32 = jb * 32;
    // stage K tile (32 rows x 256 k = 1024 16B chunks) and Vt tile
    // (256 d x 32 j = 1024 chunks); xor-swizzle on the *global* address so
    // the LDS side stays wave-uniform-base + lane*16.
#pragma unroll
    for (int i = 0; i < 4; ++i) {
      int chunk = t + 256 * i;
      int row = chunk >> 5, slot = chunk & 31;
      int gc = slot ^ row;
      gload_lds16(Kg + (size_t)(j32 + row) * DM + gc * 8, Ksh + (size_t)chunk * 8);
    }
#pragma unroll
    for (int i = 0; i < 4; ++i) {
      int chunk = t + 256 * i;
      int d = chunk >> 2, slot = chunk & 3;
      int gj = slot ^ (d & 3);
      gload_lds16(Vtg + (size_t)d * NT + j32 + gj * 8, Vsh + (size_t)chunk * 8);
    }
    __syncthreads();
    if (j32 <= rw0 + 15) {  // wave has at least one unmasked (row, col) pair
      // dropout bits for this lane's row, 32 j's, from the L2-hot bitmask
      unsigned int bits = bm[(size_t)myrow * 256 + (j32 >> 5)];
      // S^T = K Q^T: 2 j-tiles of 16. Lane holds S[myrow][j32+ct*16+q*4+r].
      f32x4 s[2] = {};
#pragma unroll
      for (int st = 0; st < 8; ++st) {
        int kc = st * 4 + q;
#pragma unroll
        for (int ct = 0; ct < 2; ++ct) {
          int jr = ct * 16 + m;
          bf16x8 a = *(const bf16x8*)&Ksh[(jr * 32 + (kc ^ jr)) * 8];
          s[ct] = MFMA16(a, qf[st], s[ct]);
        }
      }
      // causal mask
      if (j32 + 31 > rw0) {
#pragma unroll
        for (int ct = 0; ct < 2; ++ct)
#pragma unroll
          for (int r = 0; r < 4; ++r)
            if (j32 + ct * 16 + q * 4 + r > myrow) s[ct][r] = NEG_INF;
      }
      // online softmax: row = lane (scalar state). Reduce across q-lanes only.
      float mx = fmaxf(fmaxf(fmaxf(s[0][0], s[0][1]), fmaxf(s[0][2], s[0][3])),
                       fmaxf(fmaxf(s[1][0], s[1][1]), fmaxf(s[1][2], s[1][3])));
      mx = fmaxf(mx, __shfl_xor(mx, 16));
      mx = fmaxf(mx, __shfl_xor(mx, 32));
      float mn = fmaxf(mrun, mx);
      float alpha = exp2_fast(mrun - mn);
      mrun = mn;
#pragma unroll
      for (int ct = 0; ct < 2; ++ct)
#pragma unroll
        for (int r = 0; r < 4; ++r) s[ct][r] = exp2_fast(s[ct][r] - mn);
      float rs = (s[0][0] + s[0][1]) + (s[0][2] + s[0][3]) +
                 (s[1][0] + s[1][1]) + (s[1][2] + s[1][3]);
      rs += __shfl_xor(rs, 16);
      rs += __shfl_xor(rs, 32);
      lrun = lrun * alpha + rs;
#pragma unroll
      for (int ct = 0; ct < 16; ++ct)
#pragma unroll
        for (int r = 0; r < 4; ++r) oacc[ct][r] *= alpha;
      // dropout + P -> wave-private LDS (row-major [16][32], 16B-chunk swizzle)
      unsigned short* P = Psh[w];
#pragma unroll
      for (int ct = 0; ct < 2; ++ct) {
        unsigned int bb = bits >> (ct * 16 + q * 4);
        unsigned long long pk = 0;
#pragma unroll
        for (int r = 0; r < 4; ++r) {
          float pv = ((bb >> r) & 1u) ? s[ct][r] * 2.0f : 0.0f;
          pk |= (unsigned long long)f2bf_bits(pv) << (16 * r);
        }
        int c = ct * 2 + (q >> 1);  // 16B chunk within row (j/8)
        *(unsigned long long*)&P[m * 32 + ((c ^ (m & 3)) << 3) + ((q & 1) << 2)] = pk;
      }
      asm volatile("s_waitcnt lgkmcnt(0)" ::: "memory");
      // P^T B-frag: lane (m,q) needs P[m][q*8 .. q*8+7] = swizzled chunk q
      bf16x8 pf = *(const bf16x8*)&P[m * 32 + ((q ^ (m & 3)) << 3)];
      // O^T += V^T P^T: A = Vt rows (d = ct*16+m), k = 32 j's (one MFMA/ct)
#pragma unroll
      for (int ct = 0; ct < 16; ++ct) {
        int d = ct * 16 + m;
        bf16x8 a = *(const bf16x8*)&Vsh[(d * 4 + (q ^ (d & 3))) * 8];
        oacc[ct] = MFMA16(a, pf, oacc[ct]);
      }
    }
    __syncthreads();  // staging of next tile must not overwrite live K/V
  }
  // write segment partials. g = segment slot for (ib, seg).
  const int a_ = ib >> 3, r_ = ib & 7;
  const int g = 4 * a_ * (a_ + 1) + r_ * (a_ + 1) + seg;
  if (q == 0) {
    float* mlb = ml_out + ((size_t)g * 64 + 16 * w + m) * 2;
    mlb[0] = mrun;
    mlb[1] = lrun;
  }
  unsigned short* ab = acc_out + ((size_t)g * 64 + 16 * w + m) * DM;
#pragma unroll
  for (int ct = 0; ct < 16; ++ct) {
    unsigned long long pk = 0;
#pragma unroll
    for (int r = 0; r < 4; ++r)
      pk |= (unsigned long long)f2bf_bits(oacc[ct][r]) << (16 * r);
    *(unsigned long long*)&ab[ct * 16 + q * 4] = pk;  // 8B contiguous quads
  }
}

// ---------------------------------------------------------------------------
// Kernel 3: combine segment partials. O = sum_s w_s*acc_s / sum_s w_s*l_s,
// w_s = 2^(m_s - M). grid 256 blocks x 256 thr; thread = (row, 32-col group).
// ---------------------------------------------------------------------------
__global__ __launch_bounds__(256) void combine_kernel(
    const float* __restrict__ ml, const unsigned short* __restrict__ pacc,
    float* __restrict__ out) {
  const int t = threadIdx.x;
  const int row = blockIdx.x * 32 + (t >> 3);
  const int cg = (t & 7) * 32;
  const int ib = row >> 6, rib = row & 63;
  const int a = ib >> 3, r = ib & 7;
  const int g0 = 4 * a * (a + 1) + r * (a + 1);
  const int ns = a + 1;
  float M = -1e30f;
  for (int s = 0; s < ns; ++s) M = fmaxf(M, ml[((size_t)(g0 + s) * 64 + rib) * 2]);
  float Wd = 0.f;
  float acc[32];
#pragma unroll
  for (int j = 0; j < 32; ++j) acc[j] = 0.f;
  for (int s = 0; s < ns; ++s) {
    const float* mls = ml + ((size_t)(g0 + s) * 64 + rib) * 2;
    float wv = exp2_fast(mls[0] - M);
    Wd += wv * mls[1];
    const unsigned short* pa = pacc + ((size_t)(g0 + s) * 64 + rib) * DM + cg;
#pragma unroll
    for (int v4 = 0; v4 < 4; ++v4) {
      bf16x8 b = *(const bf16x8*)(pa + v4 * 8);
#pragma unroll
      for (int j = 0; j < 8; ++j) acc[v4 * 8 + j] += wv * (float)b[j];
    }
  }
  float inv = 1.0f / Wd;
#pragma unroll
  for (int j = 0; j < 32; ++j) out[(size_t)row * DM + cg + j] = acc[j] * inv;
}

// ---------------------------------------------------------------------------
extern "C" void kernel_launch(void* const* d_in, const int* in_sizes, int n_in,
                              void* d_out, int out_size, void* d_ws, size_t ws_size,
                              hipStream_t stream) {
  const float* X  = (const float*)d_in[0];
  const float* Wq = (const float*)d_in[1];
  const float* Wk = (const float*)d_in[2];
  const float* Wv = (const float*)d_in[3];
  const void* mask = d_in[4];
  float* out = (float*)d_out;

  char* ws = (char*)d_ws;
  int* flag = (int*)ws;
  unsigned short* Qs = (unsigned short*)(ws + 4096);
  unsigned short* Kb = Qs + (size_t)NT * DM;
  unsigned short* Vt = Kb + (size_t)NT * DM;
  float* ml = (float*)(Vt + (size_t)NT * DM);
  unsigned short* pacc = (unsigned short*)(ml + (size_t)1088 * 64 * 2);
  unsigned long long* bmw = (unsigned long long*)((char*)pacc + (size_t)1088 * 64 * DM * 2);
  // total ws use: 4096 + 12 MiB + 544 KiB + 34 MiB + 8 MiB ~= 55 MiB

  detect_kernel<<<1, 256, 0, stream>>>((const unsigned int*)mask, flag);
  maskpack_kernel<<<2048, 256, 0, stream>>>(mask, flag, bmw);
  proj_kernel<<<dim3(128, 3), 256, 0, stream>>>(X, Wq, Wk, Wv, Qs, Kb, Vt);
  flash_kernel<<<dim3(128, 16), 256, 0, stream>>>(Qs, Kb, Vt, (const unsigned int*)bmw,
                                                  ml, pacc);
  combine_kernel<<<256, 256, 0, stream>>>(ml, pacc, out);
}

// Round 4
// 519.926 us; speedup vs baseline: 1.5273x; 1.0145x over previous
//
#include <hip/hip_runtime.h>

// Problem constants (N=8192 tokens, D=256 model dim, dropout p=0.5 -> keep scale 2.0)
#define NT 8192
#define DM 256

typedef float f32x16 __attribute__((ext_vector_type(16)));
typedef float f32x4 __attribute__((ext_vector_type(4)));
typedef __bf16 bf16x8 __attribute__((ext_vector_type(8)));

#define MFMA32(a, b, c) __builtin_amdgcn_mfma_f32_32x32x16_bf16((a), (b), (c), 0, 0, 0)
#define MFMA16(a, b, c) __builtin_amdgcn_mfma_f32_16x16x32_bf16((a), (b), (c), 0, 0, 0)
#define NEG_INF (-__builtin_inff())

static __device__ __forceinline__ unsigned short f2bf_bits(float f) {
  return __builtin_bit_cast(unsigned short, (__bf16)f);
}
static __device__ __forceinline__ float exp2_fast(float x) {
  return __builtin_amdgcn_exp2f(x);
}
// async global->LDS, 16B per lane. LDS dest is wave-uniform base + lane*16.
static __device__ __forceinline__ void gload_lds16(const void* g, void* l) {
  __builtin_amdgcn_global_load_lds(
      (const __attribute__((address_space(1))) unsigned int*)g,
      (__attribute__((address_space(3))) unsigned int*)l, 16, 0, 0);
}

// ---------------------------------------------------------------------------
// Kernel 0: classify drop_mask storage. 1 = int32 {0,1}, 2 = float32 {0,1.0f},
// 0 = uint8 bytes. Scans first 256 dwords. (Only element size matters below.)
// ---------------------------------------------------------------------------
__global__ void detect_kernel(const unsigned int* __restrict__ m, int* __restrict__ flag) {
  __shared__ int s01, sf;
  int t = threadIdx.x;
  if (t == 0) { s01 = 1; sf = 1; }
  __syncthreads();
  unsigned int v = m[t];
  if (v > 1u) atomicAnd(&s01, 0);
  if (v != 0u && v != 0x3F800000u) atomicAnd(&sf, 0);
  __syncthreads();
  if (t == 0) *flag = s01 ? 1 : (sf ? 2 : 0);
}

// ---------------------------------------------------------------------------
// Kernel 0b: compress drop_mask (lower triangle only) into a bitmask,
// bm[i] = 8192 bits (128 u64 words). Pure streaming, ballot-based.
// ---------------------------------------------------------------------------
__global__ __launch_bounds__(256) void maskpack_kernel(
    const void* __restrict__ mask, const int* __restrict__ flagp,
    unsigned long long* __restrict__ bm) {
  const int t = threadIdx.x, lane = t & 63, w = t >> 6;
  const int r = blockIdx.x + (w << 11);  // grid 2048 -> rows r, r+2048, ...
  const int mode = *flagp;               // 0 = 1-byte elements, else 4-byte
  const int jmax = ((r >> 6) + 1) << 6;  // cover cols 0..r (round up to 64)
  unsigned long long* out = bm + (size_t)r * 128;
  if (mode == 0) {
    const unsigned char* mk = (const unsigned char*)mask + (size_t)r * NT;
    for (int j = 0; j < jmax; j += 64) {
      unsigned long long b = __ballot(mk[j + lane] != 0);
      if (lane == 0) out[j >> 6] = b;
    }
  } else {
    const unsigned int* mk = (const unsigned int*)mask + (size_t)r * NT;
    for (int j = 0; j < jmax; j += 64) {
      unsigned long long b = __ballot(mk[j + lane] != 0u);
      if (lane == 0) out[j >> 6] = b;
    }
  }
}

// ---------------------------------------------------------------------------
// Kernel 1: QKV projection. X[8192][256] f32, W[256][256] f32 (torch layout,
// out = X @ W^T). Outputs bf16: Qs (pre-scaled by log2(e)/16), K, and V stored
// transposed Vt[256][8192]. grid (128 row-blocks, 3 mats), block 256.
// ---------------------------------------------------------------------------
__global__ __launch_bounds__(256) void proj_kernel(
    const float* __restrict__ X, const float* __restrict__ Wq,
    const float* __restrict__ Wk, const float* __restrict__ Wv,
    unsigned short* __restrict__ Qs, unsigned short* __restrict__ Kb,
    unsigned short* __restrict__ Vt) {
  __shared__ __align__(16) unsigned short Xs[64 * 256];
  __shared__ __align__(16) unsigned short Ws[64 * 256];
  __shared__ float Tr[4][32 * 33];
  const int ib = blockIdx.x, mat = blockIdx.y;
  const float* W = (mat == 0) ? Wq : (mat == 1) ? Wk : Wv;
  // fold softmax scale (1/sqrt(256)) and log2(e) into Q via Wq
  const float wscale = (mat == 0) ? 0.09016844005556021f : 1.0f;
  const int t = threadIdx.x;
  const int lane = t & 63, w = t >> 6;
  const int m = lane & 31, half = lane >> 5;
  const int i0 = ib * 64;
#pragma unroll
  for (int cc = 0; cc < 8; ++cc) {
    int chunk = t + 256 * cc;
    int rr = chunk >> 5, c = chunk & 31;
    const float4* src = (const float4*)(X + (size_t)(i0 + rr) * 256 + c * 8);
    float4 f0 = src[0], f1 = src[1];
    bf16x8 v;
    v[0] = (__bf16)f0.x; v[1] = (__bf16)f0.y; v[2] = (__bf16)f0.z; v[3] = (__bf16)f0.w;
    v[4] = (__bf16)f1.x; v[5] = (__bf16)f1.y; v[6] = (__bf16)f1.z; v[7] = (__bf16)f1.w;
    *(bf16x8*)&Xs[(rr * 32 + (c ^ (rr & 31))) * 8] = v;
  }
  const int wr = w >> 1, wc = w & 1;
  for (int cb = 0; cb < 4; ++cb) {
    __syncthreads();
#pragma unroll
    for (int cc = 0; cc < 8; ++cc) {
      int chunk = t + 256 * cc;
      int rr = chunk >> 5, c = chunk & 31;
      const float4* src = (const float4*)(W + (size_t)(cb * 64 + rr) * 256 + c * 8);
      float4 f0 = src[0], f1 = src[1];
      bf16x8 v;
      v[0] = (__bf16)(f0.x * wscale); v[1] = (__bf16)(f0.y * wscale);
      v[2] = (__bf16)(f0.z * wscale); v[3] = (__bf16)(f0.w * wscale);
      v[4] = (__bf16)(f1.x * wscale); v[5] = (__bf16)(f1.y * wscale);
      v[6] = (__bf16)(f1.z * wscale); v[7] = (__bf16)(f1.w * wscale);
      *(bf16x8*)&Ws[(rr * 32 + (c ^ (rr & 31))) * 8] = v;
    }
    __syncthreads();
    f32x16 acc = {};
    const int ar = 32 * wr + m;
    const int br = 32 * wc + m;
#pragma unroll
    for (int st = 0; st < 16; ++st) {
      int kc = st * 2 + half;
      bf16x8 a = *(const bf16x8*)&Xs[(ar * 32 + (kc ^ (ar & 31))) * 8];
      bf16x8 b = *(const bf16x8*)&Ws[(br * 32 + (kc ^ (br & 31))) * 8];
      acc = MFMA32(a, b, acc);
    }
    if (mat < 2) {
      unsigned short* O = mat ? Kb : Qs;
#pragma unroll
      for (int r = 0; r < 16; ++r) {
        int row = i0 + 32 * wr + (r & 3) + 8 * (r >> 2) + 4 * half;
        int col = cb * 64 + 32 * wc + m;
        O[(size_t)row * DM + col] = f2bf_bits(acc[r]);
      }
    } else {
      float* T = Tr[w];
#pragma unroll
      for (int r = 0; r < 16; ++r) {
        int rl = (r & 3) + 8 * (r >> 2) + 4 * half;
        T[m * 33 + rl] = acc[r];
      }
      asm volatile("s_waitcnt lgkmcnt(0)" ::: "memory");
#pragma unroll
      for (int q = 0; q < 16; ++q) {
        int dl = 2 * q + half;
        float val = T[dl * 33 + m];
        Vt[(size_t)(cb * 64 + 32 * wc + dl) * NT + i0 + 32 * wr + m] = f2bf_bits(val);
      }
      asm volatile("s_waitcnt lgkmcnt(0)" ::: "memory");
    }
  }
}

// ---------------------------------------------------------------------------
// Kernel 2: flash attention, causal, post-softmax dropout (p=0.5 -> x2).
// v4: double-buffered K/V staging with raw s_barrier + manual vmcnt(8) so
// next-tile global_load_lds DMA stays in flight across the barrier (v3's
// __syncthreads forced vmcnt(0) drains each tile). One barrier per tile.
// Transposed MFMA layout (S^T = K Q^T, O^T = V^T P^T): lane owns one query
// row -> scalar m/l, per-lane bitmask dropout, 8B output stores.
// LDS 68 KiB -> 2 blocks/CU. Alpha-rescale skipped when running max is
// unchanged across the whole wave (__all), ~80% of tiles.
// Lane mapping (16x16x32): m=lane&15, q=lane>>4.
//   A[m][q*8+j], B[q*8+j][m], D[q*4+reg][m].
// ---------------------------------------------------------------------------
__global__ __launch_bounds__(256, 2) void flash_kernel(
    const unsigned short* __restrict__ Qs, const unsigned short* __restrict__ Kg,
    const unsigned short* __restrict__ Vtg, const unsigned int* __restrict__ bm,
    float* __restrict__ ml_out, unsigned short* __restrict__ acc_out) {
  __shared__ __align__(16) unsigned short Ksh[2][32 * 256];  // 2 x 16 KiB
  __shared__ __align__(16) unsigned short Vsh[2][256 * 32];  // 2 x 16 KiB
  __shared__ __align__(16) unsigned short Psh[4][16 * 32];   // 4 KiB, per-wave
  const int ib = blockIdx.x;
  const int seg = blockIdx.y;
  const int jb_end = 2 * (ib + 1);   // 32-col tiles
  const int jb0 = seg * 16;
  if (jb0 >= jb_end) return;
  const int jb1 = (jb0 + 16 < jb_end) ? jb0 + 16 : jb_end;
  const int t = threadIdx.x, lane = t & 63, w = t >> 6;
  const int m = lane & 15, q = lane >> 4;
  const int i0 = ib * 64, rw0 = i0 + 16 * w;
  const int myrow = rw0 + m;

  // Q B-fragments, register resident (16 rows x 256 k per wave -> 32 VGPRs)
  bf16x8 qf[8];
  {
    const unsigned short* qp = Qs + (size_t)myrow * DM + q * 8;
#pragma unroll
    for (int st = 0; st < 8; ++st) qf[st] = *(const bf16x8*)(qp + st * 32);
  }
  f32x4 oacc[16] = {};          // O^T: d = ct*16 + q*4 + r, row i = myrow
  float mrun = -1e30f, lrun = 0.f;

  // prologue: stage tile jb0 into buffer 0
  {
    const int j32 = jb0 * 32;
#pragma unroll
    for (int i = 0; i < 4; ++i) {
      int chunk = t + 256 * i;
      int row = chunk >> 5, slot = chunk & 31;
      int gc = slot ^ row;
      gload_lds16(Kg + (size_t)(j32 + row) * DM + gc * 8, &Ksh[0][(size_t)chunk * 8]);
    }
#pragma unroll
    for (int i = 0; i < 4; ++i) {
      int chunk = t + 256 * i;
      int d = chunk >> 2, slot = chunk & 3;
      int gj = slot ^ (d & 3);
      gload_lds16(Vtg + (size_t)d * NT + j32 + gj * 8, &Vsh[0][(size_t)chunk * 8]);
    }
  }

  for (int jb = jb0; jb < jb1; ++jb) {
    const int buf = (jb - jb0) & 1;
    const int j32 = jb * 32;
    // raw barrier: all waves finished reading buf^1 (compute jb-1). No vmcnt
    // drain here -- the prefetch DMA stays in flight across the barrier.
    asm volatile("s_barrier" ::: "memory");
    // dropout bits for this lane's row (issued before next stage so the
    // ordered vmcnt(8) below drains it together with tile jb's loads)
    unsigned int bits = bm[(size_t)myrow * 256 + (j32 >> 5)];
    if (jb + 1 < jb1) {
      const int j32n = j32 + 32;
#pragma unroll
      for (int i = 0; i < 4; ++i) {
        int chunk = t + 256 * i;
        int row = chunk >> 5, slot = chunk & 31;
        int gc = slot ^ row;
        gload_lds16(Kg + (size_t)(j32n + row) * DM + gc * 8,
                    &Ksh[buf ^ 1][(size_t)chunk * 8]);
      }
#pragma unroll
      for (int i = 0; i < 4; ++i) {
        int chunk = t + 256 * i;
        int d = chunk >> 2, slot = chunk & 3;
        int gj = slot ^ (d & 3);
        gload_lds16(Vtg + (size_t)d * NT + j32n + gj * 8,
                    &Vsh[buf ^ 1][(size_t)chunk * 8]);
      }
      // drain tile jb's 8 loads (+ bits); keep tile jb+1's 8 in flight
      asm volatile("s_waitcnt vmcnt(8)" ::: "memory");
    } else {
      asm volatile("s_waitcnt vmcnt(0)" ::: "memory");
    }
    if (j32 <= rw0 + 15) {  // wave has at least one unmasked (row, col) pair
      const unsigned short* Kb_ = Ksh[buf];
      const unsigned short* Vb_ = Vsh[buf];
      // S^T = K Q^T: 2 j-tiles of 16. Lane holds S[myrow][j32+ct*16+q*4+r].
      f32x4 s[2] = {};
#pragma unroll
      for (int st = 0; st < 8; ++st) {
        int kc = st * 4 + q;
#pragma unroll
        for (int ct = 0; ct < 2; ++ct) {
          int jr = ct * 16 + m;
          bf16x8 a = *(const bf16x8*)&Kb_[(jr * 32 + (kc ^ jr)) * 8];
          s[ct] = MFMA16(a, qf[st], s[ct]);
        }
      }
      // causal mask
      if (j32 + 31 > rw0) {
#pragma unroll
        for (int ct = 0; ct < 2; ++ct)
#pragma unroll
          for (int r = 0; r < 4; ++r)
            if (j32 + ct * 16 + q * 4 + r > myrow) s[ct][r] = NEG_INF;
      }
      // online softmax: row = lane (scalar state). Reduce across q-lanes only.
      float mx = fmaxf(fmaxf(fmaxf(s[0][0], s[0][1]), fmaxf(s[0][2], s[0][3])),
                       fmaxf(fmaxf(s[1][0], s[1][1]), fmaxf(s[1][2], s[1][3])));
      mx = fmaxf(mx, __shfl_xor(mx, 16));
      mx = fmaxf(mx, __shfl_xor(mx, 32));
      const float mn = fmaxf(mrun, mx);
#pragma unroll
      for (int ct = 0; ct < 2; ++ct)
#pragma unroll
        for (int r = 0; r < 4; ++r) s[ct][r] = exp2_fast(s[ct][r] - mn);
      float rs = (s[0][0] + s[0][1]) + (s[0][2] + s[0][3]) +
                 (s[1][0] + s[1][1]) + (s[1][2] + s[1][3]);
      rs += __shfl_xor(rs, 16);
      rs += __shfl_xor(rs, 32);
      if (__all(mn == mrun)) {
        lrun += rs;                       // running max unchanged: skip rescale
      } else {
        float alpha = exp2_fast(mrun - mn);
        lrun = lrun * alpha + rs;
#pragma unroll
        for (int ct = 0; ct < 16; ++ct)
#pragma unroll
          for (int r = 0; r < 4; ++r) oacc[ct][r] *= alpha;
        mrun = mn;
      }
      // dropout + P -> wave-private LDS (row-major [16][32], 16B-chunk swizzle)
      unsigned short* P = Psh[w];
#pragma unroll
      for (int ct = 0; ct < 2; ++ct) {
        unsigned int bb = bits >> (ct * 16 + q * 4);
        unsigned long long pk = 0;
#pragma unroll
        for (int r = 0; r < 4; ++r) {
          float pv = ((bb >> r) & 1u) ? s[ct][r] * 2.0f : 0.0f;
          pk |= (unsigned long long)f2bf_bits(pv) << (16 * r);
        }
        int c = ct * 2 + (q >> 1);  // 16B chunk within row (j/8)
        *(unsigned long long*)&P[m * 32 + ((c ^ (m & 3)) << 3) + ((q & 1) << 2)] = pk;
      }
      asm volatile("s_waitcnt lgkmcnt(0)" ::: "memory");
      // P^T B-frag: lane (m,q) needs P[m][q*8 .. q*8+7] = swizzled chunk q
      bf16x8 pf = *(const bf16x8*)&P[m * 32 + ((q ^ (m & 3)) << 3)];
      // O^T += V^T P^T: A = Vt rows (d = ct*16+m), k = 32 j's (one MFMA/ct)
#pragma unroll
      for (int ct = 0; ct < 16; ++ct) {
        int d = ct * 16 + m;
        bf16x8 a = *(const bf16x8*)&Vb_[(d * 4 + (q ^ (d & 3))) * 8];
        oacc[ct] = MFMA16(a, pf, oacc[ct]);
      }
    }
  }
  // write segment partials. g = segment slot for (ib, seg).
  const int a_ = ib >> 3, r_ = ib & 7;
  const int g = 4 * a_ * (a_ + 1) + r_ * (a_ + 1) + seg;
  if (q == 0) {
    float* mlb = ml_out + ((size_t)g * 64 + 16 * w + m) * 2;
    mlb[0] = mrun;
    mlb[1] = lrun;
  }
  unsigned short* ab = acc_out + ((size_t)g * 64 + 16 * w + m) * DM;
#pragma unroll
  for (int ct = 0; ct < 16; ++ct) {
    unsigned long long pk = 0;
#pragma unroll
    for (int r = 0; r < 4; ++r)
      pk |= (unsigned long long)f2bf_bits(oacc[ct][r]) << (16 * r);
    *(unsigned long long*)&ab[ct * 16 + q * 4] = pk;  // 8B contiguous quads
  }
}

// ---------------------------------------------------------------------------
// Kernel 3: combine segment partials. O = sum_s w_s*acc_s / sum_s w_s*l_s,
// w_s = 2^(m_s - M). grid 256 blocks x 256 thr; thread = (row, 32-col group).
// ---------------------------------------------------------------------------
__global__ __launch_bounds__(256) void combine_kernel(
    const float* __restrict__ ml, const unsigned short* __restrict__ pacc,
    float* __restrict__ out) {
  const int t = threadIdx.x;
  const int row = blockIdx.x * 32 + (t >> 3);
  const int cg = (t & 7) * 32;
  const int ib = row >> 6, rib = row & 63;
  const int a = ib >> 3, r = ib & 7;
  const int g0 = 4 * a * (a + 1) + r * (a + 1);
  const int ns = a + 1;
  float M = -1e30f;
  for (int s = 0; s < ns; ++s) M = fmaxf(M, ml[((size_t)(g0 + s) * 64 + rib) * 2]);
  float Wd = 0.f;
  float acc[32];
#pragma unroll
  for (int j = 0; j < 32; ++j) acc[j] = 0.f;
  for (int s = 0; s < ns; ++s) {
    const float* mls = ml + ((size_t)(g0 + s) * 64 + rib) * 2;
    float wv = exp2_fast(mls[0] - M);
    Wd += wv * mls[1];
    const unsigned short* pa = pacc + ((size_t)(g0 + s) * 64 + rib) * DM + cg;
#pragma unroll
    for (int v4 = 0; v4 < 4; ++v4) {
      bf16x8 b = *(const bf16x8*)(pa + v4 * 8);
#pragma unroll
      for (int j = 0; j < 8; ++j) acc[v4 * 8 + j] += wv * (float)b[j];
    }
  }
  float inv = 1.0f / Wd;
#pragma unroll
  for (int j = 0; j < 32; ++j) out[(size_t)row * DM + cg + j] = acc[j] * inv;
}

// ---------------------------------------------------------------------------
extern "C" void kernel_launch(void* const* d_in, const int* in_sizes, int n_in,
                              void* d_out, int out_size, void* d_ws, size_t ws_size,
                              hipStream_t stream) {
  const float* X  = (const float*)d_in[0];
  const float* Wq = (const float*)d_in[1];
  const float* Wk = (const float*)d_in[2];
  const float* Wv = (const float*)d_in[3];
  const void* mask = d_in[4];
  float* out = (float*)d_out;

  char* ws = (char*)d_ws;
  int* flag = (int*)ws;
  unsigned short* Qs = (unsigned short*)(ws + 4096);
  unsigned short* Kb = Qs + (size_t)NT * DM;
  unsigned short* Vt = Kb + (size_t)NT * DM;
  float* ml = (float*)(Vt + (size_t)NT * DM);
  unsigned short* pacc = (unsigned short*)(ml + (size_t)1088 * 64 * 2);
  unsigned long long* bmw = (unsigned long long*)((char*)pacc + (size_t)1088 * 64 * DM * 2);
  // total ws use: 4096 + 12 MiB + 544 KiB + 34 MiB + 8 MiB ~= 55 MiB

  detect_kernel<<<1, 256, 0, stream>>>((const unsigned int*)mask, flag);
  maskpack_kernel<<<2048, 256, 0, stream>>>(mask, flag, bmw);
  proj_kernel<<<dim3(128, 3), 256, 0, stream>>>(X, Wq, Wk, Wv, Qs, Kb, Vt);
  flash_kernel<<<dim3(128, 16), 256, 0, stream>>>(Qs, Kb, Vt, (const unsigned int*)bmw,
                                                  ml, pacc);
  combine_kernel<<<256, 256, 0, stream>>>(ml, pacc, out);
}